// Round 20
// baseline (96.287 us; speedup 1.0000x reference)
//
#include <hip/hip_runtime.h>
#include <hip/hip_bf16.h>

#define BQ 4
#define SQ 4096
#define DQ 256
#define N3 768
#define KBLK 64
#define NITER (SQ / KBLK)
#define KHALF (NITER / 2)
#define LOG2E 1.44269504f
#define THR2 11.5415603f  // 8 * log2(e)

typedef __attribute__((ext_vector_type(8))) _Float16 f16x8;
typedef __attribute__((ext_vector_type(4))) float f32x4;
typedef __attribute__((ext_vector_type(4))) unsigned int u32x4;

__device__ __forceinline__ short f2h(float f) {
  _Float16 h = (_Float16)f;
  union { _Float16 h; short s; } v; v.h = h;
  return v.s;
}

__device__ __forceinline__ void gload16(const void* g, void* lds) {
  __builtin_amdgcn_global_load_lds(
      (const __attribute__((address_space(1))) unsigned int*)g,
      (__attribute__((address_space(3))) unsigned int*)lds, 16, 0, 0);
}

// ---- prep: blocks 0..47 transpose/convert Wqkv -> W16T; block 48 = Wcomb ----
__global__ __launch_bounds__(256) void prep_kernel(
    const float* __restrict__ Wqkv, const float* __restrict__ Wproj,
    const float* __restrict__ bproj, const float* __restrict__ Wfc,
    const float* __restrict__ bfc, short* __restrict__ W16T,
    float* __restrict__ Wc) {
  const int t = threadIdx.x;
  if (blockIdx.x == 48) {
    __shared__ float wf[256];
    wf[t] = Wfc[t];
    __syncthreads();
    float acc = 0.f;
    for (int j = 0; j < 256; ++j) acc += Wproj[(size_t)t * 256 + j] * wf[j];
    Wc[t] = acc;
    if (t == 0) {
      float c = bfc[0];
      for (int j = 0; j < 256; ++j) c += bproj[j] * wf[j];
      Wc[256] = c;
    }
    return;
  }
  __shared__ float tile[64][65];
  const int nb = (blockIdx.x % 12) * 64;
  const int kb = (blockIdx.x / 12) * 64;
  const int tr = t >> 6, tc = t & 63;
#pragma unroll
  for (int i = 0; i < 16; ++i)
    tile[tr + i * 4][tc] = Wqkv[(size_t)(kb + tr + i * 4) * N3 + nb + tc];
  __syncthreads();
#pragma unroll
  for (int i = 0; i < 16; ++i)
    W16T[(size_t)(nb + tr + i * 4) * 256 + kb + tc] = f2h(tile[tc][tr + i * 4]);
}

// ---------------- QKV projection: single-barrier pipeline + coalesced stores
// K columns pre-scaled by log2(e) so attention can use native exp2.
// Shared memory: one flat region S. Loop layout: xs [64][264] @0 (16896 sh),
// ws [2][64][256] @16896 (32768 sh). Epilogue re-aliases S as [64][520]
// row-major Q|K scratch for fully-coalesced dwordx4 stores.
__global__ __launch_bounds__(1024, 4) void qkv_kernel(
    const float* __restrict__ x, const short* __restrict__ W16T,
    const float* __restrict__ bqkv, const float* __restrict__ Wc,
    short* __restrict__ Qb, short* __restrict__ Kb, float* __restrict__ u) {
  __shared__ short S[49664];          // 97 KB: xs + ws(dbuf)
  __shared__ float u_red[4][4][16];
#define XSP(m, k) (&S[(m)*264 + (k)])
#define WSP(bf, n, k) (&S[16896 + (bf)*16384 + (n)*256 + (k)])
  const int t = threadIdx.x;
  const int l = t & 63, w = t >> 6;
  const int lr = l & 15, lg = l >> 4;
  const int mq = w >> 2, nq = w & 3;
  const int Mbase = blockIdx.x * 64;

#define STAGE_W(BUF, NT)                                                      \
  {                                                                           \
    _Pragma("unroll") for (int i = 0; i < 2; ++i) {                           \
      const int n = w * 4 + i * 2 + (l >> 5);                                 \
      const int gc = (l & 31) ^ (n & 7);                                      \
      gload16(W16T + (size_t)((NT)*64 + n) * 256 + gc * 8,                    \
              WSP(BUF, w * 4 + i * 2, 0));                                    \
    }                                                                         \
  }

  STAGE_W(0, 0);

  // stage x tile (plain LDS writes)
  {
    const int m = t >> 4, kc = (t & 15) * 16;
    const float* src = x + (size_t)(Mbase + m) * DQ + kc;
    short tmp[16];
#pragma unroll
    for (int i = 0; i < 16; ++i) tmp[i] = f2h(src[i]);
    *(u32x4*)XSP(m, kc) = *(u32x4*)&tmp[0];
    *(u32x4*)XSP(m, kc + 8) = *(u32x4*)&tmp[8];
  }

  // preload all bias/Wc values (keeps in-loop VM queue = staging only)
  float bias_qk[8], bias_u[4], wc_u[4];
#pragma unroll
  for (int i = 0; i < 8; ++i) bias_qk[i] = bqkv[i * 64 + nq * 16 + lr];
#pragma unroll
  for (int i = 0; i < 4; ++i) {
    bias_u[i] = bqkv[512 + i * 64 + nq * 16 + lr];
    wc_u[i] = Wc[i * 64 + nq * 16 + lr];
  }

  unsigned qksto[8][2];
  float upart[4] = {0.f, 0.f, 0.f, 0.f};

#pragma unroll
  for (int nt = 0; nt < 12; ++nt) {
    const int cur = nt & 1;
    // own prior-tile loads landed + xs visible; block rendezvous
    asm volatile("s_waitcnt vmcnt(0) lgkmcnt(0)" ::: "memory");
    __builtin_amdgcn_s_barrier();
    __builtin_amdgcn_sched_barrier(0);
    if (nt + 1 < 12) STAGE_W(cur ^ 1, nt + 1);  // flies over compute below

    f32x4 acc = {};
    const char* wR = (const char*)WSP(cur, nq * 16 + lr, 0);
#pragma unroll
    for (int kk = 0; kk < 8; ++kk) {
      f16x8 af = *(f16x8*)XSP(mq * 16 + lr, kk * 32 + lg * 8);
      f16x8 bfr = *(const f16x8*)(wR + (((4 * kk + lg) ^ (lr & 7)) << 4));
      acc = __builtin_amdgcn_mfma_f32_16x16x32_f16(af, bfr, acc, 0, 0, 0);
    }
    if (nt < 8) {
      const float sc = (nt < 4) ? 1.f : LOG2E;  // K pre-scaled for exp2
      unsigned s0 = (unsigned short)f2h((acc[0] + bias_qk[nt]) * sc);
      unsigned s1 = (unsigned short)f2h((acc[1] + bias_qk[nt]) * sc);
      unsigned s2 = (unsigned short)f2h((acc[2] + bias_qk[nt]) * sc);
      unsigned s3 = (unsigned short)f2h((acc[3] + bias_qk[nt]) * sc);
      qksto[nt][0] = s0 | (s1 << 16);
      qksto[nt][1] = s2 | (s3 << 16);
    } else {
#pragma unroll
      for (int r = 0; r < 4; ++r) upart[r] += (acc[r] + bias_u[nt - 8]) * wc_u[nt - 8];
    }
  }

  __syncthreads();  // all ws/xs reads done: S reusable as store scratch

  // ---- epilogue: C-frags -> LDS scratch [64][520] -> coalesced stores ----
#pragma unroll
  for (int nt = 0; nt < 8; ++nt) {
    const int col = nt * 64 + nq * 16 + lr;
#pragma unroll
    for (int r = 0; r < 4; ++r) {
      const int row = mq * 16 + lg * 4 + r;
      S[row * 520 + col] =
          (short)((qksto[nt][r >> 1] >> ((r & 1) * 16)) & 0xFFFF);
    }
  }
  __syncthreads();
  {
    const int row = t >> 4, ch = t & 15;  // 16 threads per row
    const size_t gq = (size_t)(Mbase + row) * DQ;
    // Q: cols [0,256): two 16-lane-contiguous 256B segments
    *(u32x4*)(Qb + gq + ch * 8) = *(u32x4*)&S[row * 520 + ch * 8];
    *(u32x4*)(Qb + gq + 128 + ch * 8) = *(u32x4*)&S[row * 520 + 128 + ch * 8];
    // K: cols [256,512)
    *(u32x4*)(Kb + gq + ch * 8) = *(u32x4*)&S[row * 520 + 256 + ch * 8];
    *(u32x4*)(Kb + gq + 128 + ch * 8) = *(u32x4*)&S[row * 520 + 384 + ch * 8];
  }

  // u reduction
#pragma unroll
  for (int mask = 1; mask <= 8; mask <<= 1)
#pragma unroll
    for (int r = 0; r < 4; ++r) upart[r] += __shfl_xor(upart[r], mask, 64);
  if (lr == 0) {
#pragma unroll
    for (int r = 0; r < 4; ++r) u_red[mq][nq][lg * 4 + r] = upart[r];
  }
  __syncthreads();
  if (t < 64)
    u[Mbase + t] = u_red[t >> 4][0][t & 15] + u_red[t >> 4][1][t & 15] +
                   u_red[t >> 4][2][t & 15] + u_red[t >> 4][3][t & 15];
#undef STAGE_W
#undef XSP
#undef WSP
}

// -------- Flash attention: 8 waves, SINGLE barrier/iter, VALU diet ---------
// (r19 verbatim -- 60.2 us plateau; 4 structural variants all 60.3 +/- 0.3)
__global__ __launch_bounds__(512, 4) void attn_kernel(
    const short* __restrict__ Qb, const short* __restrict__ Kb,
    const float* __restrict__ u, float* __restrict__ Pm,
    float* __restrict__ Pd, float* __restrict__ Pn) {
  __shared__ short Ks[2][64][256];     // [buf][key][d], XOR-swizzled chunks
  __shared__ __align__(16) float u_lds[2048];
  __shared__ float Mrg[2][4][32][3];   // [qg][h][row]{m,den,num}

  const int t = threadIdx.x;
  const int l = t & 63, w = t >> 6;
  const int lr = l & 15, lg = l >> 4;
  const int qg = w >> 2, h = w & 3;
  const int bid = blockIdx.x;
  const int b = bid & 3;
  const int half = (bid >> 2) & 1;     // bid%8 -> XCD: one (b,half) per XCD
  const int qbase = (bid >> 3) * 64;

  const short* kbase = Kb + ((size_t)b * SQ + (size_t)half * (SQ / 2)) * DQ;
  const float* ubase = u + (size_t)b * SQ + half * (SQ / 2);

#define STAGE(BUF, KB)                                                      \
  {                                                                         \
    _Pragma("unroll") for (int i = 0; i < 4; ++i) {                         \
      const int kr = w * 8 + i * 2 + (l >> 5);                              \
      const int gc = (l & 31) ^ (kr & 7);                                   \
      gload16(kbase + (size_t)((KB)*64 + kr) * DQ + gc * 8,                 \
              &Ks[BUF][w * 8 + i * 2][0]);                                  \
    }                                                                       \
  }

  STAGE(0, 0);
  // stage this (b,half)'s u slice: wave w covers floats w*256..+255
  gload16(ubase + w * 256 + (l << 2), &u_lds[w * 256]);

  // Q fragments (B-operand): wave's 32 q-rows (qg), qrow = mm*16+lr
  f16x8 qf[2][8];
#pragma unroll
  for (int mm = 0; mm < 2; ++mm) {
    const short* qptr = Qb + (size_t)(b * SQ + qbase + qg * 32 + mm * 16 + lr) * DQ;
#pragma unroll
    for (int kk = 0; kk < 8; ++kk)
      qf[mm][kk] = *(const f16x8*)(qptr + kk * 32 + lg * 8);
  }

  // hoist loop-invariant XOR-swizzled fragment offsets
  int koff[8];
#pragma unroll
  for (int kk = 0; kk < 8; ++kk) koff[kk] = ((4 * kk + lg) ^ (lr & 7)) << 4;

  float m_run[2] = {-1e30f, -1e30f};
  float num[2] = {0.f, 0.f}, den[2] = {0.f, 0.f};

  for (int kb = 0; kb < KHALF; ++kb) {
    const int cur = kb & 1;
    asm volatile("s_waitcnt vmcnt(0)" ::: "memory");
    __builtin_amdgcn_s_barrier();
    __builtin_amdgcn_sched_barrier(0);
    if (kb + 1 < KHALF) STAGE(cur ^ 1, kb + 1);  // flies over compute below

    // S^T = K Q^T on this wave's 16 keys (2 independent 8-deep chains)
    const char* kR = (const char*)&Ks[cur][h * 16 + lr][0];
    f32x4 s[2] = {};
    __builtin_amdgcn_s_setprio(1);
#pragma unroll
    for (int kk = 0; kk < 8; ++kk) {
      f16x8 kf = *(const f16x8*)(kR + koff[kk]);
      s[0] = __builtin_amdgcn_mfma_f32_16x16x32_f16(kf, qf[0][kk], s[0], 0, 0, 0);
      s[1] = __builtin_amdgcn_mfma_f32_16x16x32_f16(kf, qf[1][kk], s[1], 0, 0, 0);
    }
    __builtin_amdgcn_s_setprio(0);

    // max-tree gate, defer-max online softmax (base 2)
    float mx[2];
#pragma unroll
    for (int mm = 0; mm < 2; ++mm)
      mx[mm] = fmaxf(fmaxf(s[mm][0], s[mm][1]), fmaxf(s[mm][2], s[mm][3]));
    const bool over = (mx[0] > m_run[0] + THR2) || (mx[1] > m_run[1] + THR2);
    if (__any(over)) {
#pragma unroll
      for (int mm = 0; mm < 2; ++mm) {
        float mt = mx[mm];
        mt = fmaxf(mt, __shfl_xor(mt, 16, 64));
        mt = fmaxf(mt, __shfl_xor(mt, 32, 64));
        const float mn = fmaxf(m_run[mm], mt);
        const float sc = __builtin_amdgcn_exp2f(m_run[mm] - mn);
        m_run[mm] = mn;
        num[mm] *= sc;
        den[mm] *= sc;
      }
    }
    {
      const f32x4 uv = *(const f32x4*)&u_lds[kb * 64 + h * 16 + lg * 4];
#pragma unroll
      for (int mm = 0; mm < 2; ++mm)
#pragma unroll
        for (int r = 0; r < 4; ++r) {
          const float p = __builtin_amdgcn_exp2f(s[mm][r] - m_run[mm]);
          den[mm] += p;
          num[mm] += p * uv[r];
        }
    }
  }

  // reduce per-lane partials over the lg axis (keys)
#pragma unroll
  for (int mm = 0; mm < 2; ++mm) {
    num[mm] += __shfl_xor(num[mm], 16, 64);
    num[mm] += __shfl_xor(num[mm], 32, 64);
    den[mm] += __shfl_xor(den[mm], 16, 64);
    den[mm] += __shfl_xor(den[mm], 32, 64);
  }
  if (lg == 0) {
#pragma unroll
    for (int mm = 0; mm < 2; ++mm) {
      Mrg[qg][h][mm * 16 + lr][0] = m_run[mm];
      Mrg[qg][h][mm * 16 + lr][1] = den[mm];
      Mrg[qg][h][mm * 16 + lr][2] = num[mm];
    }
  }
  __syncthreads();

  if (t < 64) {
    const int row = t & 31, qg2 = t >> 5;
    float M = Mrg[qg2][0][row][0];
#pragma unroll
    for (int hh = 1; hh < 4; ++hh) M = fmaxf(M, Mrg[qg2][hh][row][0]);
    float dt = 0.f, nt = 0.f;
#pragma unroll
    for (int hh = 0; hh < 4; ++hh) {
      const float e = __builtin_amdgcn_exp2f(Mrg[qg2][hh][row][0] - M);
      dt += e * Mrg[qg2][hh][row][1];
      nt += e * Mrg[qg2][hh][row][2];
    }
    const size_t idx = (size_t)half * (BQ * SQ) + (size_t)b * SQ + qbase + row +
                       qg2 * 32;
    Pm[idx] = M; Pd[idx] = dt; Pn[idx] = nt;
  }
#undef STAGE
}

// ---------------- merge the 2 key-halves ----------------
__global__ void merge_kernel(const float* __restrict__ Pm,
                             const float* __restrict__ Pd,
                             const float* __restrict__ Pn,
                             const float* __restrict__ Wc,
                             float* __restrict__ out) {
  const int gid = blockIdx.x * 256 + threadIdx.x;
  const float m0 = Pm[gid], m1 = Pm[BQ * SQ + gid];
  const float M = fmaxf(m0, m1);
  const float e0 = __builtin_amdgcn_exp2f(m0 - M);
  const float e1 = __builtin_amdgcn_exp2f(m1 - M);
  const float den = e0 * Pd[gid] + e1 * Pd[BQ * SQ + gid];
  const float num = e0 * Pn[gid] + e1 * Pn[BQ * SQ + gid];
  out[gid] = num / den + Wc[256];
}

// ---------------- launch ----------------
extern "C" void kernel_launch(void* const* d_in, const int* in_sizes, int n_in,
                              void* d_out, int out_size, void* d_ws, size_t ws_size,
                              hipStream_t stream) {
  const float* x     = (const float*)d_in[0];
  const float* Wqkv  = (const float*)d_in[1];
  const float* bqkv  = (const float*)d_in[2];
  const float* Wproj = (const float*)d_in[3];
  const float* bproj = (const float*)d_in[4];
  const float* Wfc   = (const float*)d_in[5];
  const float* bfc   = (const float*)d_in[6];
  float* out = (float*)d_out;

  const size_t SEG = (size_t)BQ * SQ * DQ * 2;  // 8 MB per fp16 tensor
  char* wsb = (char*)d_ws;
  short* Qb   = (short*)(wsb);
  short* Kb   = (short*)(wsb + SEG);
  char* base  = wsb + 2 * SEG;
  float* Wc   = (float*)(base);                          // 257 f
  float* u    = (float*)(base + 4096);                   // 16384 f
  short* W16T = (short*)(base + 4096 + 65536);           // 384 KB
  float* Pm   = (float*)(base + 4096 + 65536 + 393216);  // 32768 f
  float* Pd   = Pm + 2 * BQ * SQ;
  float* Pn   = Pd + 2 * BQ * SQ;

  prep_kernel<<<49, 256, 0, stream>>>(Wqkv, Wproj, bproj, Wfc, bfc, W16T, Wc);
  qkv_kernel<<<256, 1024, 0, stream>>>(x, W16T, bqkv, Wc, Qb, Kb, u);
  attn_kernel<<<512, 512, 0, stream>>>(Qb, Kb, u, Pm, Pd, Pn);
  merge_kernel<<<BQ * SQ / 256, 256, 0, stream>>>(Pm, Pd, Pn, Wc, out);
}

// Round 21
// 93.319 us; speedup vs baseline: 1.0318x; 1.0318x over previous
//
#include <hip/hip_runtime.h>
#include <hip/hip_bf16.h>

#define BQ 4
#define SQ 4096
#define DQ 256
#define N3 768
#define KBLK 64
#define NITER (SQ / KBLK)
#define KHALF (NITER / 2)
#define LOG2E 1.44269504f
#define THR2 11.5415603f  // 8 * log2(e)

typedef __attribute__((ext_vector_type(8))) _Float16 f16x8;
typedef __attribute__((ext_vector_type(4))) float f32x4;
typedef __attribute__((ext_vector_type(4))) unsigned int u32x4;

__device__ __forceinline__ short f2h(float f) {
  _Float16 h = (_Float16)f;
  union { _Float16 h; short s; } v; v.h = h;
  return v.s;
}

__device__ __forceinline__ void gload16(const void* g, void* lds) {
  __builtin_amdgcn_global_load_lds(
      (const __attribute__((address_space(1))) unsigned int*)g,
      (__attribute__((address_space(3))) unsigned int*)lds, 16, 0, 0);
}

// ---- prep: blocks 0..47 transpose/convert Wqkv -> W16T; block 48 = Wcomb ----
__global__ __launch_bounds__(256) void prep_kernel(
    const float* __restrict__ Wqkv, const float* __restrict__ Wproj,
    const float* __restrict__ bproj, const float* __restrict__ Wfc,
    const float* __restrict__ bfc, short* __restrict__ W16T,
    float* __restrict__ Wc) {
  const int t = threadIdx.x;
  if (blockIdx.x == 48) {
    __shared__ float wf[256];
    wf[t] = Wfc[t];
    __syncthreads();
    float acc = 0.f;
    for (int j = 0; j < 256; ++j) acc += Wproj[(size_t)t * 256 + j] * wf[j];
    Wc[t] = acc;
    if (t == 0) {
      float c = bfc[0];
      for (int j = 0; j < 256; ++j) c += bproj[j] * wf[j];
      Wc[256] = c;
    }
    return;
  }
  __shared__ float tile[64][65];
  const int nb = (blockIdx.x % 12) * 64;
  const int kb = (blockIdx.x / 12) * 64;
  const int tr = t >> 6, tc = t & 63;
#pragma unroll
  for (int i = 0; i < 16; ++i)
    tile[tr + i * 4][tc] = Wqkv[(size_t)(kb + tr + i * 4) * N3 + nb + tc];
  __syncthreads();
#pragma unroll
  for (int i = 0; i < 16; ++i)
    W16T[(size_t)(nb + tr + i * 4) * 256 + kb + tc] = f2h(tile[tc][tr + i * 4]);
}

// ---------------- QKV projection (r16 verbatim -- 93.8 total baseline) ------
__global__ __launch_bounds__(1024, 4) void qkv_kernel(
    const float* __restrict__ x, const short* __restrict__ W16T,
    const float* __restrict__ bqkv, const float* __restrict__ Wc,
    short* __restrict__ Qb, short* __restrict__ Kb, float* __restrict__ u) {
  __shared__ short xs[64][264];       // [m][k] fp16, pitch 528B
  __shared__ short ws[2][64][256];    // [buf][n][k], XOR-swizzled chunks
  __shared__ float u_red[4][4][16];
  const int t = threadIdx.x;
  const int l = t & 63, w = t >> 6;
  const int lr = l & 15, lg = l >> 4;
  const int mq = w >> 2, nq = w & 3;
  const int Mbase = blockIdx.x * 64;

#define STAGE_W(BUF, NT)                                                      \
  {                                                                           \
    _Pragma("unroll") for (int i = 0; i < 2; ++i) {                           \
      const int n = w * 4 + i * 2 + (l >> 5);                                 \
      const int gc = (l & 31) ^ (n & 7);                                      \
      gload16(W16T + (size_t)((NT)*64 + n) * 256 + gc * 8,                    \
              &ws[BUF][w * 4 + i * 2][0]);                                    \
    }                                                                         \
  }

  STAGE_W(0, 0);

  // stage x tile (plain LDS writes)
  {
    const int m = t >> 4, kc = (t & 15) * 16;
    const float* src = x + (size_t)(Mbase + m) * DQ + kc;
    short tmp[16];
#pragma unroll
    for (int i = 0; i < 16; ++i) tmp[i] = f2h(src[i]);
    *(u32x4*)&xs[m][kc] = *(u32x4*)&tmp[0];
    *(u32x4*)&xs[m][kc + 8] = *(u32x4*)&tmp[8];
  }

  // preload all bias/Wc values (keeps in-loop VM queue = staging only)
  float bias_qk[8], bias_u[4], wc_u[4];
#pragma unroll
  for (int i = 0; i < 8; ++i) bias_qk[i] = bqkv[i * 64 + nq * 16 + lr];
#pragma unroll
  for (int i = 0; i < 4; ++i) {
    bias_u[i] = bqkv[512 + i * 64 + nq * 16 + lr];
    wc_u[i] = Wc[i * 64 + nq * 16 + lr];
  }

  __syncthreads();  // drains prologue (ws buf0 + xs + preloads)

  unsigned qksto[8][2];
  float upart[4] = {0.f, 0.f, 0.f, 0.f};

#pragma unroll
  for (int nt = 0; nt < 12; ++nt) {
    const int cur = nt & 1;
    if (nt + 1 < 12) {
      STAGE_W(cur ^ 1, nt + 1);
      asm volatile("s_waitcnt vmcnt(2)" ::: "memory");
    } else {
      asm volatile("s_waitcnt vmcnt(0)" ::: "memory");
    }
    __builtin_amdgcn_s_barrier();
    __builtin_amdgcn_sched_barrier(0);

    f32x4 acc = {};
    const char* wR = (const char*)&ws[cur][nq * 16 + lr][0];
#pragma unroll
    for (int kk = 0; kk < 8; ++kk) {
      f16x8 af = *(f16x8*)&xs[mq * 16 + lr][kk * 32 + lg * 8];
      f16x8 bfr = *(const f16x8*)(wR + (((4 * kk + lg) ^ (lr & 7)) << 4));
      acc = __builtin_amdgcn_mfma_f32_16x16x32_f16(af, bfr, acc, 0, 0, 0);
    }
    if (nt < 8) {
      const float sc = (nt < 4) ? 1.f : LOG2E;  // K pre-scaled for exp2
      unsigned s0 = (unsigned short)f2h((acc[0] + bias_qk[nt]) * sc);
      unsigned s1 = (unsigned short)f2h((acc[1] + bias_qk[nt]) * sc);
      unsigned s2 = (unsigned short)f2h((acc[2] + bias_qk[nt]) * sc);
      unsigned s3 = (unsigned short)f2h((acc[3] + bias_qk[nt]) * sc);
      qksto[nt][0] = s0 | (s1 << 16);
      qksto[nt][1] = s2 | (s3 << 16);
    } else {
#pragma unroll
      for (int r = 0; r < 4; ++r) upart[r] += (acc[r] + bias_u[nt - 8]) * wc_u[nt - 8];
    }
    __builtin_amdgcn_s_barrier();
  }

  // epilogue: Q/K stores
#pragma unroll
  for (int nt = 0; nt < 8; ++nt) {
    const int col = nt * 64 + nq * 16 + lr;
#pragma unroll
    for (int r = 0; r < 4; ++r) {
      const int row = Mbase + mq * 16 + lg * 4 + r;
      const short sv = (short)((qksto[nt][r >> 1] >> ((r & 1) * 16)) & 0xFFFF);
      if (col < 256) Qb[(size_t)row * DQ + col] = sv;
      else           Kb[(size_t)row * DQ + (col - 256)] = sv;
    }
  }

  // u reduction
#pragma unroll
  for (int mask = 1; mask <= 8; mask <<= 1)
#pragma unroll
    for (int r = 0; r < 4; ++r) upart[r] += __shfl_xor(upart[r], mask, 64);
  if (lr == 0) {
#pragma unroll
    for (int r = 0; r < 4; ++r) u_red[mq][nq][lg * 4 + r] = upart[r];
  }
  __syncthreads();
  if (t < 64)
    u[Mbase + t] = u_red[t >> 4][0][t & 15] + u_red[t >> 4][1][t & 15] +
                   u_red[t >> 4][2][t & 15] + u_red[t >> 4][3][t & 15];
#undef STAGE_W
}

// ------- Flash attention: 4 waves x (64q x 16k) -- K-traffic 8 B/cell -------
// grid 512 (2 blocks/CU), 256 thr = 4 waves = 4 key-quarters; each wave holds
// ALL 64 q-rows in regs (qf[4][8] = 128 VGPR). Q frags loaded FROM LDS
// (staged into Ks[0], later clobbered by K staging -> compiler cannot
// rematerialize; registers forced resident). Single-barrier loop (r19).
__global__ __launch_bounds__(256, 2) void attn_kernel(
    const short* __restrict__ Qb, const short* __restrict__ Kb,
    const float* __restrict__ u, float* __restrict__ Pm,
    float* __restrict__ Pd, float* __restrict__ Pn) {
  __shared__ short Ks[2][64][256];     // [buf][key][d], XOR-swizzled chunks
  __shared__ __align__(16) float u_lds[2048];
  __shared__ float Mrg[4][64][3];      // [h][row]{m,den,num}

  const int t = threadIdx.x;
  const int l = t & 63, w = t >> 6;    // w = key-quarter h
  const int lr = l & 15, lg = l >> 4;
  const int bid = blockIdx.x;
  const int b = bid & 3;
  const int half = (bid >> 2) & 1;     // bid%8 -> XCD: one (b,half) per XCD
  const int qbase = (bid >> 3) * 64;

  const short* kbase = Kb + ((size_t)b * SQ + (size_t)half * (SQ / 2)) * DQ;
  const float* ubase = u + (size_t)b * SQ + half * (SQ / 2);

#define STAGE(BUF, KB)                                                      \
  {                                                                         \
    _Pragma("unroll") for (int i = 0; i < 8; ++i) {                         \
      const int kr = w * 16 + i * 2 + (l >> 5);                             \
      const int gc = (l & 31) ^ (kr & 7);                                   \
      gload16(kbase + (size_t)((KB)*64 + kr) * DQ + gc * 8,                 \
              &Ks[BUF][w * 16 + i * 2][0]);                                 \
    }                                                                       \
  }

  // ---- prologue: stage Q tile into Ks[0] (same XOR swizzle) + u slice ----
  {
    const short* qsrc = Qb + (size_t)(b * SQ + qbase) * DQ;
#pragma unroll
    for (int i = 0; i < 8; ++i) {
      const int qr = w * 16 + i * 2 + (l >> 5);
      const int gc = (l & 31) ^ (qr & 7);
      gload16(qsrc + (size_t)qr * DQ + gc * 8, &Ks[0][w * 16 + i * 2][0]);
    }
  }
  gload16(ubase + w * 256 + (l << 2), &u_lds[w * 256]);
  gload16(ubase + (4 + w) * 256 + (l << 2), &u_lds[(4 + w) * 256]);

  // hoist loop-invariant XOR-swizzled fragment offsets
  int koff[8];
#pragma unroll
  for (int kk = 0; kk < 8; ++kk) koff[kk] = ((4 * kk + lg) ^ (lr & 7)) << 4;

  asm volatile("s_waitcnt vmcnt(0)" ::: "memory");
  __syncthreads();  // Q tile + u landed

  // Q fragments from LDS: q-row = mm*16+lr, all 64 q-rows per wave
  f16x8 qf[4][8];
#pragma unroll
  for (int mm = 0; mm < 4; ++mm) {
    const char* qR = (const char*)&Ks[0][mm * 16 + lr][0];
#pragma unroll
    for (int kk = 0; kk < 8; ++kk)
      qf[mm][kk] = *(const f16x8*)(qR + koff[kk]);
  }
  __syncthreads();  // all qf reads done before K staging clobbers Ks[0]

  float m_run[4] = {-1e30f, -1e30f, -1e30f, -1e30f};
  float num[4] = {}, den[4] = {};

  STAGE(0, 0);  // first K tile

  for (int kb = 0; kb < KHALF; ++kb) {
    const int cur = kb & 1;
    asm volatile("s_waitcnt vmcnt(0)" ::: "memory");
    __builtin_amdgcn_s_barrier();
    __builtin_amdgcn_sched_barrier(0);
    if (kb + 1 < KHALF) STAGE(cur ^ 1, kb + 1);  // flies over compute below

    // S^T = K Q^T: wave's 16 keys x 64 q (4 independent 8-deep chains)
    const char* kR = (const char*)&Ks[cur][w * 16 + lr][0];
    f32x4 s[4] = {};
    __builtin_amdgcn_s_setprio(1);
#pragma unroll
    for (int kk = 0; kk < 8; ++kk) {
      f16x8 kf = *(const f16x8*)(kR + koff[kk]);
      s[0] = __builtin_amdgcn_mfma_f32_16x16x32_f16(kf, qf[0][kk], s[0], 0, 0, 0);
      s[1] = __builtin_amdgcn_mfma_f32_16x16x32_f16(kf, qf[1][kk], s[1], 0, 0, 0);
      s[2] = __builtin_amdgcn_mfma_f32_16x16x32_f16(kf, qf[2][kk], s[2], 0, 0, 0);
      s[3] = __builtin_amdgcn_mfma_f32_16x16x32_f16(kf, qf[3][kk], s[3], 0, 0, 0);
    }
    __builtin_amdgcn_s_setprio(0);

    // max-tree gate, defer-max online softmax (base 2)
    float mx[4];
#pragma unroll
    for (int mm = 0; mm < 4; ++mm)
      mx[mm] = fmaxf(fmaxf(s[mm][0], s[mm][1]), fmaxf(s[mm][2], s[mm][3]));
    const bool over = (mx[0] > m_run[0] + THR2) || (mx[1] > m_run[1] + THR2) ||
                      (mx[2] > m_run[2] + THR2) || (mx[3] > m_run[3] + THR2);
    if (__any(over)) {
#pragma unroll
      for (int mm = 0; mm < 4; ++mm) {
        float mt = mx[mm];
        mt = fmaxf(mt, __shfl_xor(mt, 16, 64));
        mt = fmaxf(mt, __shfl_xor(mt, 32, 64));
        const float mn = fmaxf(m_run[mm], mt);
        const float sc = __builtin_amdgcn_exp2f(m_run[mm] - mn);
        m_run[mm] = mn;
        num[mm] *= sc;
        den[mm] *= sc;
      }
    }
    {
      const f32x4 uv = *(const f32x4*)&u_lds[kb * 64 + w * 16 + lg * 4];
#pragma unroll
      for (int mm = 0; mm < 4; ++mm)
#pragma unroll
        for (int r = 0; r < 4; ++r) {
          const float p = __builtin_amdgcn_exp2f(s[mm][r] - m_run[mm]);
          den[mm] += p;
          num[mm] += p * uv[r];
        }
    }
  }

  // reduce per-lane partials over the lg axis (keys)
#pragma unroll
  for (int mm = 0; mm < 4; ++mm) {
    num[mm] += __shfl_xor(num[mm], 16, 64);
    num[mm] += __shfl_xor(num[mm], 32, 64);
    den[mm] += __shfl_xor(den[mm], 16, 64);
    den[mm] += __shfl_xor(den[mm], 32, 64);
  }
  if (lg == 0) {
#pragma unroll
    for (int mm = 0; mm < 4; ++mm) {
      Mrg[w][mm * 16 + lr][0] = m_run[mm];
      Mrg[w][mm * 16 + lr][1] = den[mm];
      Mrg[w][mm * 16 + lr][2] = num[mm];
    }
  }
  __syncthreads();

  if (t < 64) {
    float M = Mrg[0][t][0];
#pragma unroll
    for (int hh = 1; hh < 4; ++hh) M = fmaxf(M, Mrg[hh][t][0]);
    float dt = 0.f, nt = 0.f;
#pragma unroll
    for (int hh = 0; hh < 4; ++hh) {
      const float e = __builtin_amdgcn_exp2f(Mrg[hh][t][0] - M);
      dt += e * Mrg[hh][t][1];
      nt += e * Mrg[hh][t][2];
    }
    const size_t idx = (size_t)half * (BQ * SQ) + (size_t)b * SQ + qbase + t;
    Pm[idx] = M; Pd[idx] = dt; Pn[idx] = nt;
  }
#undef STAGE
}

// ---------------- merge the 2 key-halves ----------------
__global__ void merge_kernel(const float* __restrict__ Pm,
                             const float* __restrict__ Pd,
                             const float* __restrict__ Pn,
                             const float* __restrict__ Wc,
                             float* __restrict__ out) {
  const int gid = blockIdx.x * 256 + threadIdx.x;
  const float m0 = Pm[gid], m1 = Pm[BQ * SQ + gid];
  const float M = fmaxf(m0, m1);
  const float e0 = __builtin_amdgcn_exp2f(m0 - M);
  const float e1 = __builtin_amdgcn_exp2f(m1 - M);
  const float den = e0 * Pd[gid] + e1 * Pd[BQ * SQ + gid];
  const float num = e0 * Pn[gid] + e1 * Pn[BQ * SQ + gid];
  out[gid] = num / den + Wc[256];
}

// ---------------- launch ----------------
extern "C" void kernel_launch(void* const* d_in, const int* in_sizes, int n_in,
                              void* d_out, int out_size, void* d_ws, size_t ws_size,
                              hipStream_t stream) {
  const float* x     = (const float*)d_in[0];
  const float* Wqkv  = (const float*)d_in[1];
  const float* bqkv  = (const float*)d_in[2];
  const float* Wproj = (const float*)d_in[3];
  const float* bproj = (const float*)d_in[4];
  const float* Wfc   = (const float*)d_in[5];
  const float* bfc   = (const float*)d_in[6];
  float* out = (float*)d_out;

  const size_t SEG = (size_t)BQ * SQ * DQ * 2;  // 8 MB per fp16 tensor
  char* wsb = (char*)d_ws;
  short* Qb   = (short*)(wsb);
  short* Kb   = (short*)(wsb + SEG);
  char* base  = wsb + 2 * SEG;
  float* Wc   = (float*)(base);                          // 257 f
  float* u    = (float*)(base + 4096);                   // 16384 f
  short* W16T = (short*)(base + 4096 + 65536);           // 384 KB
  float* Pm   = (float*)(base + 4096 + 65536 + 393216);  // 32768 f
  float* Pd   = Pm + 2 * BQ * SQ;
  float* Pn   = Pd + 2 * BQ * SQ;

  prep_kernel<<<49, 256, 0, stream>>>(Wqkv, Wproj, bproj, Wfc, bfc, W16T, Wc);
  qkv_kernel<<<256, 1024, 0, stream>>>(x, W16T, bqkv, Wc, Qb, Kb, u);
  attn_kernel<<<512, 256, 0, stream>>>(Qb, Kb, u, Pm, Pd, Pn);
  merge_kernel<<<BQ * SQ / 256, 256, 0, stream>>>(Pm, Pd, Pn, Wc, out);
}

// Round 23
// 92.645 us; speedup vs baseline: 1.0393x; 1.0073x over previous
//
#include <hip/hip_runtime.h>
#include <hip/hip_bf16.h>

#define BQ 4
#define SQ 4096
#define DQ 256
#define N3 768
#define KBLK 64
#define NITER (SQ / KBLK)
#define KHALF (NITER / 2)
#define LOG2E 1.44269504f
#define THR2 11.5415603f  // 8 * log2(e)

typedef __attribute__((ext_vector_type(8))) _Float16 f16x8;
typedef __attribute__((ext_vector_type(4))) _Float16 f16x4;
typedef __attribute__((ext_vector_type(4))) float f32x4;
typedef __attribute__((ext_vector_type(4))) unsigned int u32x4;

__device__ __forceinline__ short f2h(float f) {
  _Float16 h = (_Float16)f;
  union { _Float16 h; short s; } v; v.h = h;
  return v.s;
}

__device__ __forceinline__ void gload16(const void* g, void* lds) {
  __builtin_amdgcn_global_load_lds(
      (const __attribute__((address_space(1))) unsigned int*)g,
      (__attribute__((address_space(3))) unsigned int*)lds, 16, 0, 0);
}

// ---- prep: blocks 0..47 transpose/convert Wqkv -> W16T; block 48 = Wcomb ----
__global__ __launch_bounds__(256) void prep_kernel(
    const float* __restrict__ Wqkv, const float* __restrict__ Wproj,
    const float* __restrict__ bproj, const float* __restrict__ Wfc,
    const float* __restrict__ bfc, short* __restrict__ W16T,
    float* __restrict__ Wc) {
  const int t = threadIdx.x;
  if (blockIdx.x == 48) {
    __shared__ float wf[256];
    wf[t] = Wfc[t];
    __syncthreads();
    float acc = 0.f;
    for (int j = 0; j < 256; ++j) acc += Wproj[(size_t)t * 256 + j] * wf[j];
    Wc[t] = acc;
    if (t == 0) {
      float c = bfc[0];
      for (int j = 0; j < 256; ++j) c += bproj[j] * wf[j];
      Wc[256] = c;
    }
    return;
  }
  __shared__ float tile[64][65];
  const int nb = (blockIdx.x % 12) * 64;
  const int kb = (blockIdx.x / 12) * 64;
  const int tr = t >> 6, tc = t & 63;
#pragma unroll
  for (int i = 0; i < 16; ++i)
    tile[tr + i * 4][tc] = Wqkv[(size_t)(kb + tr + i * 4) * N3 + nb + tc];
  __syncthreads();
#pragma unroll
  for (int i = 0; i < 16; ++i)
    W16T[(size_t)(nb + tr + i * 4) * 256 + kb + tc] = f2h(tile[tc][tr + i * 4]);
}

// ---------------- QKV projection (r16 structure; u output now fp16) ---------
__global__ __launch_bounds__(1024, 4) void qkv_kernel(
    const float* __restrict__ x, const short* __restrict__ W16T,
    const float* __restrict__ bqkv, const float* __restrict__ Wc,
    short* __restrict__ Qb, short* __restrict__ Kb, short* __restrict__ u16) {
  __shared__ short xs[64][264];       // [m][k] fp16, pitch 528B
  __shared__ short ws[2][64][256];    // [buf][n][k], XOR-swizzled chunks
  __shared__ float u_red[4][4][16];
  const int t = threadIdx.x;
  const int l = t & 63, w = t >> 6;
  const int lr = l & 15, lg = l >> 4;
  const int mq = w >> 2, nq = w & 3;
  const int Mbase = blockIdx.x * 64;

#define STAGE_W(BUF, NT)                                                      \
  {                                                                           \
    _Pragma("unroll") for (int i = 0; i < 2; ++i) {                           \
      const int n = w * 4 + i * 2 + (l >> 5);                                 \
      const int gc = (l & 31) ^ (n & 7);                                      \
      gload16(W16T + (size_t)((NT)*64 + n) * 256 + gc * 8,                    \
              &ws[BUF][w * 4 + i * 2][0]);                                    \
    }                                                                         \
  }

  STAGE_W(0, 0);

  // stage x tile (plain LDS writes)
  {
    const int m = t >> 4, kc = (t & 15) * 16;
    const float* src = x + (size_t)(Mbase + m) * DQ + kc;
    short tmp[16];
#pragma unroll
    for (int i = 0; i < 16; ++i) tmp[i] = f2h(src[i]);
    *(u32x4*)&xs[m][kc] = *(u32x4*)&tmp[0];
    *(u32x4*)&xs[m][kc + 8] = *(u32x4*)&tmp[8];
  }

  // preload all bias/Wc values (keeps in-loop VM queue = staging only)
  float bias_qk[8], bias_u[4], wc_u[4];
#pragma unroll
  for (int i = 0; i < 8; ++i) bias_qk[i] = bqkv[i * 64 + nq * 16 + lr];
#pragma unroll
  for (int i = 0; i < 4; ++i) {
    bias_u[i] = bqkv[512 + i * 64 + nq * 16 + lr];
    wc_u[i] = Wc[i * 64 + nq * 16 + lr];
  }

  __syncthreads();  // drains prologue (ws buf0 + xs + preloads)

  unsigned qksto[8][2];
  float upart[4] = {0.f, 0.f, 0.f, 0.f};

#pragma unroll
  for (int nt = 0; nt < 12; ++nt) {
    const int cur = nt & 1;
    if (nt + 1 < 12) {
      STAGE_W(cur ^ 1, nt + 1);
      asm volatile("s_waitcnt vmcnt(2)" ::: "memory");
    } else {
      asm volatile("s_waitcnt vmcnt(0)" ::: "memory");
    }
    __builtin_amdgcn_s_barrier();
    __builtin_amdgcn_sched_barrier(0);

    f32x4 acc = {};
    const char* wR = (const char*)&ws[cur][nq * 16 + lr][0];
#pragma unroll
    for (int kk = 0; kk < 8; ++kk) {
      f16x8 af = *(f16x8*)&xs[mq * 16 + lr][kk * 32 + lg * 8];
      f16x8 bfr = *(const f16x8*)(wR + (((4 * kk + lg) ^ (lr & 7)) << 4));
      acc = __builtin_amdgcn_mfma_f32_16x16x32_f16(af, bfr, acc, 0, 0, 0);
    }
    if (nt < 8) {
      const float sc = (nt < 4) ? 1.f : LOG2E;  // K pre-scaled for exp2
      unsigned s0 = (unsigned short)f2h((acc[0] + bias_qk[nt]) * sc);
      unsigned s1 = (unsigned short)f2h((acc[1] + bias_qk[nt]) * sc);
      unsigned s2 = (unsigned short)f2h((acc[2] + bias_qk[nt]) * sc);
      unsigned s3 = (unsigned short)f2h((acc[3] + bias_qk[nt]) * sc);
      qksto[nt][0] = s0 | (s1 << 16);
      qksto[nt][1] = s2 | (s3 << 16);
    } else {
#pragma unroll
      for (int r = 0; r < 4; ++r) upart[r] += (acc[r] + bias_u[nt - 8]) * wc_u[nt - 8];
    }
    __builtin_amdgcn_s_barrier();
  }

  // epilogue: Q/K stores
#pragma unroll
  for (int nt = 0; nt < 8; ++nt) {
    const int col = nt * 64 + nq * 16 + lr;
#pragma unroll
    for (int r = 0; r < 4; ++r) {
      const int row = Mbase + mq * 16 + lg * 4 + r;
      const short sv = (short)((qksto[nt][r >> 1] >> ((r & 1) * 16)) & 0xFFFF);
      if (col < 256) Qb[(size_t)row * DQ + col] = sv;
      else           Kb[(size_t)row * DQ + (col - 256)] = sv;
    }
  }

  // u reduction -> fp16 output
#pragma unroll
  for (int mask = 1; mask <= 8; mask <<= 1)
#pragma unroll
    for (int r = 0; r < 4; ++r) upart[r] += __shfl_xor(upart[r], mask, 64);
  if (lr == 0) {
#pragma unroll
    for (int r = 0; r < 4; ++r) u_red[mq][nq][lg * 4 + r] = upart[r];
  }
  __syncthreads();
  if (t < 64)
    u16[Mbase + t] = f2h(u_red[t >> 4][0][t & 15] + u_red[t >> 4][1][t & 15] +
                         u_red[t >> 4][2][t & 15] + u_red[t >> 4][3][t & 15]);
#undef STAGE_W
}

// --- Flash attention: 4 waves x (64q x 16k); num/den on the MFMA pipe ------
// r21 structure. New: p -> fp16 (cvt_pkrtz); numden[mm] accumulated by
// mfma_f32_16x16x16f16 with A = [u; 1; 0...] (num=row0/reg0, den=row1/reg1).
// P's C-layout (key=lg*4+r, qrow=lr) IS the B-frag layout for K=16 -> no
// cross-lane movement. Per-qrow rescale valid (col=lr is per-lane).
__global__ __launch_bounds__(256, 2) void attn_kernel(
    const short* __restrict__ Qb, const short* __restrict__ Kb,
    const short* __restrict__ u16, float* __restrict__ Pm,
    float* __restrict__ Pd, float* __restrict__ Pn) {
  __shared__ short Ks[2][64][256];     // [buf][key][d], XOR-swizzled chunks
  __shared__ __align__(16) short u_lds[2048];  // fp16 u slice (4 KB)
  __shared__ float Mrg[4][64][3];      // [h][row]{m,den,num}

  const int t = threadIdx.x;
  const int l = t & 63, w = t >> 6;    // w = key-quarter h
  const int lr = l & 15, lg = l >> 4;
  const int bid = blockIdx.x;
  const int b = bid & 3;
  const int half = (bid >> 2) & 1;     // bid%8 -> XCD: one (b,half) per XCD
  const int qbase = (bid >> 3) * 64;

  const short* kbase = Kb + ((size_t)b * SQ + (size_t)half * (SQ / 2)) * DQ;
  const short* ubase = u16 + (size_t)b * SQ + half * (SQ / 2);

#define STAGE(BUF, KB)                                                      \
  {                                                                         \
    _Pragma("unroll") for (int i = 0; i < 8; ++i) {                         \
      const int kr = w * 16 + i * 2 + (l >> 5);                             \
      const int gc = (l & 31) ^ (kr & 7);                                   \
      gload16(kbase + (size_t)((KB)*64 + kr) * DQ + gc * 8,                 \
              &Ks[BUF][w * 16 + i * 2][0]);                                 \
    }                                                                       \
  }

  // ---- prologue: stage Q tile into Ks[0] (same XOR swizzle) + u slice ----
  {
    const short* qsrc = Qb + (size_t)(b * SQ + qbase) * DQ;
#pragma unroll
    for (int i = 0; i < 8; ++i) {
      const int qr = w * 16 + i * 2 + (l >> 5);
      const int gc = (l & 31) ^ (qr & 7);
      gload16(qsrc + (size_t)qr * DQ + gc * 8, &Ks[0][w * 16 + i * 2][0]);
    }
  }
  gload16(ubase + w * 512 + (l << 3), &u_lds[w * 512]);  // 2048 fp16 total

  // hoist loop-invariant XOR-swizzled fragment offsets
  int koff[8];
#pragma unroll
  for (int kk = 0; kk < 8; ++kk) koff[kk] = ((4 * kk + lg) ^ (lr & 7)) << 4;

  asm volatile("s_waitcnt vmcnt(0)" ::: "memory");
  __syncthreads();  // Q tile + u landed

  // Q fragments from LDS: q-row = mm*16+lr, all 64 q-rows per wave
  f16x8 qf[4][8];
#pragma unroll
  for (int mm = 0; mm < 4; ++mm) {
    const char* qR = (const char*)&Ks[0][mm * 16 + lr][0];
#pragma unroll
    for (int kk = 0; kk < 8; ++kk)
      qf[mm][kk] = *(const f16x8*)(qR + koff[kk]);
  }
  __syncthreads();  // all qf reads done before K staging clobbers Ks[0]

  float m_run[4] = {-1e30f, -1e30f, -1e30f, -1e30f};
  f32x4 numden[4] = {};  // per mm: reg0=num(row0), reg1=den(row1), rows>=2 zero

  STAGE(0, 0);  // first K tile

  for (int kb = 0; kb < KHALF; ++kb) {
    const int cur = kb & 1;
    asm volatile("s_waitcnt vmcnt(0)" ::: "memory");
    __builtin_amdgcn_s_barrier();
    __builtin_amdgcn_sched_barrier(0);
    if (kb + 1 < KHALF) STAGE(cur ^ 1, kb + 1);  // flies over compute below

    // S^T = K Q^T: wave's 16 keys x 64 q (4 independent 8-deep chains)
    const char* kR = (const char*)&Ks[cur][w * 16 + lr][0];
    f32x4 s[4] = {};
    __builtin_amdgcn_s_setprio(1);
#pragma unroll
    for (int kk = 0; kk < 8; ++kk) {
      f16x8 kf = *(const f16x8*)(kR + koff[kk]);
      s[0] = __builtin_amdgcn_mfma_f32_16x16x32_f16(kf, qf[0][kk], s[0], 0, 0, 0);
      s[1] = __builtin_amdgcn_mfma_f32_16x16x32_f16(kf, qf[1][kk], s[1], 0, 0, 0);
      s[2] = __builtin_amdgcn_mfma_f32_16x16x32_f16(kf, qf[2][kk], s[2], 0, 0, 0);
      s[3] = __builtin_amdgcn_mfma_f32_16x16x32_f16(kf, qf[3][kk], s[3], 0, 0, 0);
    }
    __builtin_amdgcn_s_setprio(0);

    // max-tree gate, defer-max online softmax (base 2)
    float mx[4];
#pragma unroll
    for (int mm = 0; mm < 4; ++mm)
      mx[mm] = fmaxf(fmaxf(s[mm][0], s[mm][1]), fmaxf(s[mm][2], s[mm][3]));
    const bool over = (mx[0] > m_run[0] + THR2) || (mx[1] > m_run[1] + THR2) ||
                      (mx[2] > m_run[2] + THR2) || (mx[3] > m_run[3] + THR2);
    if (__any(over)) {
#pragma unroll
      for (int mm = 0; mm < 4; ++mm) {
        float mt = mx[mm];
        mt = fmaxf(mt, __shfl_xor(mt, 16, 64));
        mt = fmaxf(mt, __shfl_xor(mt, 32, 64));
        const float mn = fmaxf(m_run[mm], mt);
        const float sc = __builtin_amdgcn_exp2f(m_run[mm] - mn);
        m_run[mm] = mn;
#pragma unroll
        for (int r = 0; r < 4; ++r) numden[mm][r] *= sc;
      }
    }

    // A operand: row0 = u (fp16), row1 = 1, rows 2..15 = 0
    f16x4 uf;
    {
      const f16x4 uraw = *(const f16x4*)&u_lds[kb * 64 + w * 16 + lg * 4];
#pragma unroll
      for (int j = 0; j < 4; ++j)
        uf[j] = (lr == 0) ? uraw[j]
                          : ((lr == 1) ? (_Float16)1.0f : (_Float16)0.0f);
    }

    // p = exp2(s - m) -> fp16 (pkrtz), accumulate num/den on MFMA pipe:
    // B-frag (K=16): B[key=lg*4+j][col=lr] = pf[j]  == C-layout of s. 1:1.
#pragma unroll
    for (int mm = 0; mm < 4; ++mm) {
      const float p0 = __builtin_amdgcn_exp2f(s[mm][0] - m_run[mm]);
      const float p1 = __builtin_amdgcn_exp2f(s[mm][1] - m_run[mm]);
      const float p2 = __builtin_amdgcn_exp2f(s[mm][2] - m_run[mm]);
      const float p3 = __builtin_amdgcn_exp2f(s[mm][3] - m_run[mm]);
      const auto lo = __builtin_amdgcn_cvt_pkrtz(p0, p1);  // __fp16 x2
      const auto hi = __builtin_amdgcn_cvt_pkrtz(p2, p3);
      f16x4 pf;
      pf[0] = (_Float16)lo[0]; pf[1] = (_Float16)lo[1];
      pf[2] = (_Float16)hi[0]; pf[3] = (_Float16)hi[1];
      numden[mm] = __builtin_amdgcn_mfma_f32_16x16x16f16(uf, pf, numden[mm], 0, 0, 0);
    }
  }

  // num/den are complete per qrow in lanes lg==0 (reg0=num, reg1=den)
  if (lg == 0) {
#pragma unroll
    for (int mm = 0; mm < 4; ++mm) {
      Mrg[w][mm * 16 + lr][0] = m_run[mm];
      Mrg[w][mm * 16 + lr][1] = numden[mm][1];
      Mrg[w][mm * 16 + lr][2] = numden[mm][0];
    }
  }
  __syncthreads();

  if (t < 64) {
    float M = Mrg[0][t][0];
#pragma unroll
    for (int hh = 1; hh < 4; ++hh) M = fmaxf(M, Mrg[hh][t][0]);
    float dt = 0.f, nt = 0.f;
#pragma unroll
    for (int hh = 0; hh < 4; ++hh) {
      const float e = __builtin_amdgcn_exp2f(Mrg[hh][t][0] - M);
      dt += e * Mrg[hh][t][1];
      nt += e * Mrg[hh][t][2];
    }
    const size_t idx = (size_t)half * (BQ * SQ) + (size_t)b * SQ + qbase + t;
    Pm[idx] = M; Pd[idx] = dt; Pn[idx] = nt;
  }
#undef STAGE
}

// ---------------- merge the 2 key-halves ----------------
__global__ void merge_kernel(const float* __restrict__ Pm,
                             const float* __restrict__ Pd,
                             const float* __restrict__ Pn,
                             const float* __restrict__ Wc,
                             float* __restrict__ out) {
  const int gid = blockIdx.x * 256 + threadIdx.x;
  const float m0 = Pm[gid], m1 = Pm[BQ * SQ + gid];
  const float M = fmaxf(m0, m1);
  const float e0 = __builtin_amdgcn_exp2f(m0 - M);
  const float e1 = __builtin_amdgcn_exp2f(m1 - M);
  const float den = e0 * Pd[gid] + e1 * Pd[BQ * SQ + gid];
  const float num = e0 * Pn[gid] + e1 * Pn[BQ * SQ + gid];
  out[gid] = num / den + Wc[256];
}

// ---------------- launch ----------------
extern "C" void kernel_launch(void* const* d_in, const int* in_sizes, int n_in,
                              void* d_out, int out_size, void* d_ws, size_t ws_size,
                              hipStream_t stream) {
  const float* x     = (const float*)d_in[0];
  const float* Wqkv  = (const float*)d_in[1];
  const float* bqkv  = (const float*)d_in[2];
  const float* Wproj = (const float*)d_in[3];
  const float* bproj = (const float*)d_in[4];
  const float* Wfc   = (const float*)d_in[5];
  const float* bfc   = (const float*)d_in[6];
  float* out = (float*)d_out;

  const size_t SEG = (size_t)BQ * SQ * DQ * 2;  // 8 MB per fp16 tensor
  char* wsb = (char*)d_ws;
  short* Qb   = (short*)(wsb);
  short* Kb   = (short*)(wsb + SEG);
  char* base  = wsb + 2 * SEG;
  float* Wc   = (float*)(base);                          // 257 f
  short* u16  = (short*)(base + 4096);                   // 16384 fp16
  short* W16T = (short*)(base + 4096 + 65536);           // 384 KB
  float* Pm   = (float*)(base + 4096 + 65536 + 393216);  // 32768 f
  float* Pd   = Pm + 2 * BQ * SQ;
  float* Pn   = Pd + 2 * BQ * SQ;

  prep_kernel<<<49, 256, 0, stream>>>(Wqkv, Wproj, bproj, Wfc, bfc, W16T, Wc);
  qkv_kernel<<<256, 1024, 0, stream>>>(x, W16T, bqkv, Wc, Qb, Kb, u16);
  attn_kernel<<<512, 256, 0, stream>>>(Qb, Kb, u16, Pm, Pd, Pn);
  merge_kernel<<<BQ * SQ / 256, 256, 0, stream>>>(Pm, Pd, Pn, Wc, out);
}

// Round 24
// 91.828 us; speedup vs baseline: 1.0486x; 1.0089x over previous
//
#include <hip/hip_runtime.h>
#include <hip/hip_bf16.h>

#define BQ 4
#define SQ 4096
#define DQ 256
#define N3 768
#define KBLK 64
#define NITER (SQ / KBLK)
#define KHALF (NITER / 2)
#define LOG2E 1.44269504f
#define THR2 11.5415603f  // 8 * log2(e)

typedef __attribute__((ext_vector_type(8))) _Float16 f16x8;
typedef __attribute__((ext_vector_type(4))) _Float16 f16x4;
typedef __attribute__((ext_vector_type(4))) float f32x4;
typedef __attribute__((ext_vector_type(4))) unsigned int u32x4;

__device__ __forceinline__ short f2h(float f) {
  _Float16 h = (_Float16)f;
  union { _Float16 h; short s; } v; v.h = h;
  return v.s;
}

__device__ __forceinline__ void gload16(const void* g, void* lds) {
  __builtin_amdgcn_global_load_lds(
      (const __attribute__((address_space(1))) unsigned int*)g,
      (__attribute__((address_space(3))) unsigned int*)lds, 16, 0, 0);
}

// ---- prep: blocks 0..47 transpose/convert Wqkv -> W16T; block 48 = Wcomb ----
__global__ __launch_bounds__(256) void prep_kernel(
    const float* __restrict__ Wqkv, const float* __restrict__ Wproj,
    const float* __restrict__ bproj, const float* __restrict__ Wfc,
    const float* __restrict__ bfc, short* __restrict__ W16T,
    float* __restrict__ Wc) {
  const int t = threadIdx.x;
  if (blockIdx.x == 48) {
    __shared__ float wf[256];
    wf[t] = Wfc[t];
    __syncthreads();
    float acc = 0.f;
    for (int j = 0; j < 256; ++j) acc += Wproj[(size_t)t * 256 + j] * wf[j];
    Wc[t] = acc;
    if (t == 0) {
      float c = bfc[0];
      for (int j = 0; j < 256; ++j) c += bproj[j] * wf[j];
      Wc[256] = c;
    }
    return;
  }
  __shared__ float tile[64][65];
  const int nb = (blockIdx.x % 12) * 64;
  const int kb = (blockIdx.x / 12) * 64;
  const int tr = t >> 6, tc = t & 63;
#pragma unroll
  for (int i = 0; i < 16; ++i)
    tile[tr + i * 4][tc] = Wqkv[(size_t)(kb + tr + i * 4) * N3 + nb + tc];
  __syncthreads();
#pragma unroll
  for (int i = 0; i < 16; ++i)
    W16T[(size_t)(nb + tr + i * 4) * 256 + kb + tc] = f2h(tile[tc][tr + i * 4]);
}

// ------- QKV projection: 512 blocks (32-row tiles), 2 blocks/CU -------------
// 8 waves = 2 mq x 4 nq. LDS exactly 80KB: xs [32][256] (XOR-chunk-swizzled
// content, plain ds_writes) + ws [2][64][256] (gload_lds, XOR-swizzled src).
// Single-barrier loop; u_red aliases xs region post-loop. u output fp16.
__global__ __launch_bounds__(512, 2) void qkv_kernel(
    const float* __restrict__ x, const short* __restrict__ W16T,
    const float* __restrict__ bqkv, const float* __restrict__ Wc,
    short* __restrict__ Qb, short* __restrict__ Kb, short* __restrict__ u16) {
  __shared__ short S[40960];  // 80 KB: xs @0 (8192 sh), ws @8192 (32768 sh)
#define XSP(m, k) (&S[(m)*256 + (k)])
#define WSP(bf, n, k) (&S[8192 + (bf)*16384 + (n)*256 + (k)])
  const int t = threadIdx.x;
  const int l = t & 63, w = t >> 6;
  const int lr = l & 15, lg = l >> 4;
  const int mq = w >> 2, nq = w & 3;
  const int Mbase = blockIdx.x * 32;

#define STAGE_W(BUF, NT)                                                      \
  {                                                                           \
    _Pragma("unroll") for (int i = 0; i < 4; ++i) {                           \
      const int n = w * 8 + i * 2 + (l >> 5);                                 \
      const int gc = (l & 31) ^ (n & 7);                                      \
      gload16(W16T + (size_t)((NT)*64 + n) * 256 + gc * 8,                    \
              WSP(BUF, w * 8 + i * 2, 0));                                    \
    }                                                                         \
  }

  STAGE_W(0, 0);

  // stage x tile (32 rows), content XOR-chunk-swizzled: chunk j -> j^(m&7)
  {
    const int m = t >> 4, c = t & 15;  // c = 16-element group (2 chunks)
    const float* src = x + (size_t)(Mbase + m) * DQ + c * 16;
    short tmp[16];
#pragma unroll
    for (int i = 0; i < 16; ++i) tmp[i] = f2h(src[i]);
    *(u32x4*)XSP(m, ((2 * c) ^ (m & 7)) * 8) = *(u32x4*)&tmp[0];
    *(u32x4*)XSP(m, ((2 * c + 1) ^ (m & 7)) * 8) = *(u32x4*)&tmp[8];
  }

  // preload all bias/Wc values (keeps in-loop VM queue = staging only)
  float bias_qk[8], bias_u[4], wc_u[4];
#pragma unroll
  for (int i = 0; i < 8; ++i) bias_qk[i] = bqkv[i * 64 + nq * 16 + lr];
#pragma unroll
  for (int i = 0; i < 4; ++i) {
    bias_u[i] = bqkv[512 + i * 64 + nq * 16 + lr];
    wc_u[i] = Wc[i * 64 + nq * 16 + lr];
  }

  // hoist XOR-swizzled fragment offsets (shared by xs and ws reads)
  int koff[8];
#pragma unroll
  for (int kk = 0; kk < 8; ++kk) koff[kk] = ((4 * kk + lg) ^ (lr & 7)) << 4;

  unsigned qksto[8][2];
  float upart[4] = {0.f, 0.f, 0.f, 0.f};

#pragma unroll
  for (int nt = 0; nt < 12; ++nt) {
    const int cur = nt & 1;
    // own prior-tile loads + xs writes landed; block rendezvous
    asm volatile("s_waitcnt vmcnt(0) lgkmcnt(0)" ::: "memory");
    __builtin_amdgcn_s_barrier();
    __builtin_amdgcn_sched_barrier(0);
    if (nt + 1 < 12) STAGE_W(cur ^ 1, nt + 1);  // flies over compute below

    f32x4 acc = {};
    const char* xR = (const char*)XSP(mq * 16 + lr, 0);
    const char* wR = (const char*)WSP(cur, nq * 16 + lr, 0);
#pragma unroll
    for (int kk = 0; kk < 8; ++kk) {
      f16x8 af = *(const f16x8*)(xR + koff[kk]);
      f16x8 bfr = *(const f16x8*)(wR + koff[kk]);
      acc = __builtin_amdgcn_mfma_f32_16x16x32_f16(af, bfr, acc, 0, 0, 0);
    }
    if (nt < 8) {
      const float sc = (nt < 4) ? 1.f : LOG2E;  // K pre-scaled for exp2
      unsigned s0 = (unsigned short)f2h((acc[0] + bias_qk[nt]) * sc);
      unsigned s1 = (unsigned short)f2h((acc[1] + bias_qk[nt]) * sc);
      unsigned s2 = (unsigned short)f2h((acc[2] + bias_qk[nt]) * sc);
      unsigned s3 = (unsigned short)f2h((acc[3] + bias_qk[nt]) * sc);
      qksto[nt][0] = s0 | (s1 << 16);
      qksto[nt][1] = s2 | (s3 << 16);
    } else {
#pragma unroll
      for (int r = 0; r < 4; ++r) upart[r] += (acc[r] + bias_u[nt - 8]) * wc_u[nt - 8];
    }
  }

  // epilogue: Q/K stores
#pragma unroll
  for (int nt = 0; nt < 8; ++nt) {
    const int col = nt * 64 + nq * 16 + lr;
#pragma unroll
    for (int r = 0; r < 4; ++r) {
      const int row = Mbase + mq * 16 + lg * 4 + r;
      const short sv = (short)((qksto[nt][r >> 1] >> ((r & 1) * 16)) & 0xFFFF);
      if (col < 256) Qb[(size_t)row * DQ + col] = sv;
      else           Kb[(size_t)row * DQ + (col - 256)] = sv;
    }
  }

  // u reduction -> fp16 output (u_red aliases the xs region of S)
#pragma unroll
  for (int mask = 1; mask <= 8; mask <<= 1)
#pragma unroll
    for (int r = 0; r < 4; ++r) upart[r] += __shfl_xor(upart[r], mask, 64);
  __syncthreads();  // all xs/ws reads done before aliasing S
  float* u_red = (float*)&S[0];  // [2][4][16] -> (mq*4+nq)*16 + row
  if (lr == 0) {
#pragma unroll
    for (int r = 0; r < 4; ++r)
      u_red[(mq * 4 + nq) * 16 + lg * 4 + r] = upart[r];
  }
  __syncthreads();
  if (t < 32) {
    const int g = t >> 4, row = t & 15;
    u16[Mbase + t] = f2h(u_red[(g * 4 + 0) * 16 + row] +
                         u_red[(g * 4 + 1) * 16 + row] +
                         u_red[(g * 4 + 2) * 16 + row] +
                         u_red[(g * 4 + 3) * 16 + row]);
  }
#undef STAGE_W
#undef XSP
#undef WSP
}

// --- Flash attention (r23 verbatim): 4 waves x (64q x 16k), MFMA num/den ---
__global__ __launch_bounds__(256, 2) void attn_kernel(
    const short* __restrict__ Qb, const short* __restrict__ Kb,
    const short* __restrict__ u16, float* __restrict__ Pm,
    float* __restrict__ Pd, float* __restrict__ Pn) {
  __shared__ short Ks[2][64][256];     // [buf][key][d], XOR-swizzled chunks
  __shared__ __align__(16) short u_lds[2048];  // fp16 u slice (4 KB)
  __shared__ float Mrg[4][64][3];      // [h][row]{m,den,num}

  const int t = threadIdx.x;
  const int l = t & 63, w = t >> 6;    // w = key-quarter h
  const int lr = l & 15, lg = l >> 4;
  const int bid = blockIdx.x;
  const int b = bid & 3;
  const int half = (bid >> 2) & 1;     // bid%8 -> XCD: one (b,half) per XCD
  const int qbase = (bid >> 3) * 64;

  const short* kbase = Kb + ((size_t)b * SQ + (size_t)half * (SQ / 2)) * DQ;
  const short* ubase = u16 + (size_t)b * SQ + half * (SQ / 2);

#define STAGE(BUF, KB)                                                      \
  {                                                                         \
    _Pragma("unroll") for (int i = 0; i < 8; ++i) {                         \
      const int kr = w * 16 + i * 2 + (l >> 5);                             \
      const int gc = (l & 31) ^ (kr & 7);                                   \
      gload16(kbase + (size_t)((KB)*64 + kr) * DQ + gc * 8,                 \
              &Ks[BUF][w * 16 + i * 2][0]);                                 \
    }                                                                       \
  }

  // ---- prologue: stage Q tile into Ks[0] (same XOR swizzle) + u slice ----
  {
    const short* qsrc = Qb + (size_t)(b * SQ + qbase) * DQ;
#pragma unroll
    for (int i = 0; i < 8; ++i) {
      const int qr = w * 16 + i * 2 + (l >> 5);
      const int gc = (l & 31) ^ (qr & 7);
      gload16(qsrc + (size_t)qr * DQ + gc * 8, &Ks[0][w * 16 + i * 2][0]);
    }
  }
  gload16(ubase + w * 512 + (l << 3), &u_lds[w * 512]);  // 2048 fp16 total

  // hoist loop-invariant XOR-swizzled fragment offsets
  int koff[8];
#pragma unroll
  for (int kk = 0; kk < 8; ++kk) koff[kk] = ((4 * kk + lg) ^ (lr & 7)) << 4;

  asm volatile("s_waitcnt vmcnt(0)" ::: "memory");
  __syncthreads();  // Q tile + u landed

  // Q fragments from LDS: q-row = mm*16+lr, all 64 q-rows per wave
  f16x8 qf[4][8];
#pragma unroll
  for (int mm = 0; mm < 4; ++mm) {
    const char* qR = (const char*)&Ks[0][mm * 16 + lr][0];
#pragma unroll
    for (int kk = 0; kk < 8; ++kk)
      qf[mm][kk] = *(const f16x8*)(qR + koff[kk]);
  }
  __syncthreads();  // all qf reads done before K staging clobbers Ks[0]

  float m_run[4] = {-1e30f, -1e30f, -1e30f, -1e30f};
  f32x4 numden[4] = {};  // per mm: reg0=num(row0), reg1=den(row1), rows>=2 zero

  STAGE(0, 0);  // first K tile

  for (int kb = 0; kb < KHALF; ++kb) {
    const int cur = kb & 1;
    asm volatile("s_waitcnt vmcnt(0)" ::: "memory");
    __builtin_amdgcn_s_barrier();
    __builtin_amdgcn_sched_barrier(0);
    if (kb + 1 < KHALF) STAGE(cur ^ 1, kb + 1);  // flies over compute below

    // S^T = K Q^T: wave's 16 keys x 64 q (4 independent 8-deep chains)
    const char* kR = (const char*)&Ks[cur][w * 16 + lr][0];
    f32x4 s[4] = {};
    __builtin_amdgcn_s_setprio(1);
#pragma unroll
    for (int kk = 0; kk < 8; ++kk) {
      f16x8 kf = *(const f16x8*)(kR + koff[kk]);
      s[0] = __builtin_amdgcn_mfma_f32_16x16x32_f16(kf, qf[0][kk], s[0], 0, 0, 0);
      s[1] = __builtin_amdgcn_mfma_f32_16x16x32_f16(kf, qf[1][kk], s[1], 0, 0, 0);
      s[2] = __builtin_amdgcn_mfma_f32_16x16x32_f16(kf, qf[2][kk], s[2], 0, 0, 0);
      s[3] = __builtin_amdgcn_mfma_f32_16x16x32_f16(kf, qf[3][kk], s[3], 0, 0, 0);
    }
    __builtin_amdgcn_s_setprio(0);

    // max-tree gate, defer-max online softmax (base 2)
    float mx[4];
#pragma unroll
    for (int mm = 0; mm < 4; ++mm)
      mx[mm] = fmaxf(fmaxf(s[mm][0], s[mm][1]), fmaxf(s[mm][2], s[mm][3]));
    const bool over = (mx[0] > m_run[0] + THR2) || (mx[1] > m_run[1] + THR2) ||
                      (mx[2] > m_run[2] + THR2) || (mx[3] > m_run[3] + THR2);
    if (__any(over)) {
#pragma unroll
      for (int mm = 0; mm < 4; ++mm) {
        float mt = mx[mm];
        mt = fmaxf(mt, __shfl_xor(mt, 16, 64));
        mt = fmaxf(mt, __shfl_xor(mt, 32, 64));
        const float mn = fmaxf(m_run[mm], mt);
        const float sc = __builtin_amdgcn_exp2f(m_run[mm] - mn);
        m_run[mm] = mn;
#pragma unroll
        for (int r = 0; r < 4; ++r) numden[mm][r] *= sc;
      }
    }

    // A operand: row0 = u (fp16), row1 = 1, rows 2..15 = 0
    f16x4 uf;
    {
      const f16x4 uraw = *(const f16x4*)&u_lds[kb * 64 + w * 16 + lg * 4];
#pragma unroll
      for (int j = 0; j < 4; ++j)
        uf[j] = (lr == 0) ? uraw[j]
                          : ((lr == 1) ? (_Float16)1.0f : (_Float16)0.0f);
    }

    // p = exp2(s - m) -> fp16 (pkrtz), accumulate num/den on MFMA pipe
#pragma unroll
    for (int mm = 0; mm < 4; ++mm) {
      const float p0 = __builtin_amdgcn_exp2f(s[mm][0] - m_run[mm]);
      const float p1 = __builtin_amdgcn_exp2f(s[mm][1] - m_run[mm]);
      const float p2 = __builtin_amdgcn_exp2f(s[mm][2] - m_run[mm]);
      const float p3 = __builtin_amdgcn_exp2f(s[mm][3] - m_run[mm]);
      const auto lo = __builtin_amdgcn_cvt_pkrtz(p0, p1);  // __fp16 x2
      const auto hi = __builtin_amdgcn_cvt_pkrtz(p2, p3);
      f16x4 pf;
      pf[0] = (_Float16)lo[0]; pf[1] = (_Float16)lo[1];
      pf[2] = (_Float16)hi[0]; pf[3] = (_Float16)hi[1];
      numden[mm] = __builtin_amdgcn_mfma_f32_16x16x16f16(uf, pf, numden[mm], 0, 0, 0);
    }
  }

  // num/den are complete per qrow in lanes lg==0 (reg0=num, reg1=den)
  if (lg == 0) {
#pragma unroll
    for (int mm = 0; mm < 4; ++mm) {
      Mrg[w][mm * 16 + lr][0] = m_run[mm];
      Mrg[w][mm * 16 + lr][1] = numden[mm][1];
      Mrg[w][mm * 16 + lr][2] = numden[mm][0];
    }
  }
  __syncthreads();

  if (t < 64) {
    float M = Mrg[0][t][0];
#pragma unroll
    for (int hh = 1; hh < 4; ++hh) M = fmaxf(M, Mrg[hh][t][0]);
    float dt = 0.f, nt = 0.f;
#pragma unroll
    for (int hh = 0; hh < 4; ++hh) {
      const float e = __builtin_amdgcn_exp2f(Mrg[hh][t][0] - M);
      dt += e * Mrg[hh][t][1];
      nt += e * Mrg[hh][t][2];
    }
    const size_t idx = (size_t)half * (BQ * SQ) + (size_t)b * SQ + qbase + t;
    Pm[idx] = M; Pd[idx] = dt; Pn[idx] = nt;
  }
#undef STAGE
}

// ---------------- merge the 2 key-halves ----------------
__global__ void merge_kernel(const float* __restrict__ Pm,
                             const float* __restrict__ Pd,
                             const float* __restrict__ Pn,
                             const float* __restrict__ Wc,
                             float* __restrict__ out) {
  const int gid = blockIdx.x * 256 + threadIdx.x;
  const float m0 = Pm[gid], m1 = Pm[BQ * SQ + gid];
  const float M = fmaxf(m0, m1);
  const float e0 = __builtin_amdgcn_exp2f(m0 - M);
  const float e1 = __builtin_amdgcn_exp2f(m1 - M);
  const float den = e0 * Pd[gid] + e1 * Pd[BQ * SQ + gid];
  const float num = e0 * Pn[gid] + e1 * Pn[BQ * SQ + gid];
  out[gid] = num / den + Wc[256];
}

// ---------------- launch ----------------
extern "C" void kernel_launch(void* const* d_in, const int* in_sizes, int n_in,
                              void* d_out, int out_size, void* d_ws, size_t ws_size,
                              hipStream_t stream) {
  const float* x     = (const float*)d_in[0];
  const float* Wqkv  = (const float*)d_in[1];
  const float* bqkv  = (const float*)d_in[2];
  const float* Wproj = (const float*)d_in[3];
  const float* bproj = (const float*)d_in[4];
  const float* Wfc   = (const float*)d_in[5];
  const float* bfc   = (const float*)d_in[6];
  float* out = (float*)d_out;

  const size_t SEG = (size_t)BQ * SQ * DQ * 2;  // 8 MB per fp16 tensor
  char* wsb = (char*)d_ws;
  short* Qb   = (short*)(wsb);
  short* Kb   = (short*)(wsb + SEG);
  char* base  = wsb + 2 * SEG;
  float* Wc   = (float*)(base);                          // 257 f
  short* u16  = (short*)(base + 4096);                   // 16384 fp16
  short* W16T = (short*)(base + 4096 + 65536);           // 384 KB
  float* Pm   = (float*)(base + 4096 + 65536 + 393216);  // 32768 f
  float* Pd   = Pm + 2 * BQ * SQ;
  float* Pn   = Pd + 2 * BQ * SQ;

  prep_kernel<<<49, 256, 0, stream>>>(Wqkv, Wproj, bproj, Wfc, bfc, W16T, Wc);
  qkv_kernel<<<512, 512, 0, stream>>>(x, W16T, bqkv, Wc, Qb, Kb, u16);
  attn_kernel<<<512, 256, 0, stream>>>(Qb, Kb, u16, Pm, Pd, Pn);
  merge_kernel<<<BQ * SQ / 256, 256, 0, stream>>>(Pm, Pd, Pn, Wc, out);
}